// Round 3
// baseline (302.624 us; speedup 1.0000x reference)
//
#include <hip/hip_runtime.h>

// adder2d: out[b,f,l] = -sum_k |W[f,k] - P[b,k,l]|, P = 3x3/s1/p1 im2col of x.
// M=16*784=12544, N=F=128, K=1152. fp32 exact.
// R3 design: 64x64 tile per WAVE (8x8 micro per lane, 0.25 B LDS / VALU op).
// Block = 4 waves k-splitting the same tile (private LDS regions, barrier-free
// hot loop), blockIdx.z splits channels x4. Cross-wave LDS tree-reduce, then
// atomicAdd into pre-zeroed out. No workspace, no combine kernel.

#define B_   16
#define C_   128
#define HH   28
#define WW   28
#define F_   128
#define L_   (HH * WW)         // 784
#define K_   (C_ * 9)          // 1152
#define M_   (B_ * L_)         // 12544 = 196 * 64
#define TM   64
#define TF   64
#define Z    4                 // blockIdx.z channel split
#define NW   4                 // waves per block (in-block channel split)
#define BC   2                 // channels per LDS chunk
#define KC   (BC * 9)          // 18 k-steps per chunk
#define NCHUNK (C_ / (Z * NW * BC))   // 4 chunks per wave
#define CPW    (C_ / (Z * NW))        // 8 channels per wave

__global__ __launch_bounds__(256, 4)
void adder2d_main(const float* __restrict__ x, const float* __restrict__ Wg,
                  float* __restrict__ out) {
    __shared__ float sm[2 * NW * KC * 64];     // 9216 floats = 36,864 B

    const int t    = threadIdx.x;
    const int wid  = t >> 6;
    const int lane = t & 63;
    const int tx   = lane & 7;       // m-group (8 m's)
    const int ty   = lane >> 3;      // f-group (8 f's)
    const int m0   = blockIdx.x * TM;
    const int f0   = blockIdx.y * TF;
    const int c0   = blockIdx.z * (C_ / Z) + wid * CPW;

    float* Pst = sm + wid * (KC * 64);                  // this wave's P region
    float* Wst = sm + NW * (KC * 64) + wid * (KC * 64); // this wave's W region

    // ---- staging geometry (lane-wise): lane stages column m = m0 + lane
    const int mG = m0 + lane;
    const int bI = mG / L_;
    const int lP = mG - bI * L_;
    const int ho = lP / WW;
    const int wo = lP - ho * WW;
    int  yof[3], xof[3];
    bool yok[3], xok[3];
    #pragma unroll
    for (int d = 0; d < 3; ++d) {
        const int y  = ho + d - 1;
        const int xw = wo + d - 1;
        yok[d] = (y >= 0) && (y < HH);  yof[d] = y * WW;
        xok[d] = (xw >= 0) && (xw < WW); xof[d] = xw;
    }
    const float* xb   = x  + (size_t)bI * (C_ * L_);
    const float* wrow = Wg + (size_t)(f0 + lane) * K_;  // lane = f for W staging

    float acc[8][8];
    #pragma unroll
    for (int i = 0; i < 8; ++i)
        #pragma unroll
        for (int j = 0; j < 8; ++j) acc[i][j] = 0.0f;

    for (int ch = 0; ch < NCHUNK; ++ch) {
        const int c8 = c0 + ch * BC;
        __syncthreads();                       // WAR: prior reads done before overwrite
        // stage P: rows kl=0..17, col = lane (conflict-free writes, coalesced x reads)
        const float* xc = xb + c8 * L_;
        #pragma unroll
        for (int kl = 0; kl < KC; ++kl) {
            const int cl = kl / 9, r = kl - 9 * cl;
            const int kh = r / 3,  kw = r - 3 * (r / 3);
            float v = 0.0f;
            if (yok[kh] && xok[kw]) v = xc[cl * L_ + yof[kh] + xof[kw]];
            Pst[kl * 64 + lane] = v;
        }
        // stage W: lane's filter row, 18 consecutive k (L1/L2-resident)
        const float* wc = wrow + c8 * 9;
        #pragma unroll
        for (int kl = 0; kl < KC; ++kl) Wst[kl * 64 + lane] = wc[kl];
        __syncthreads();
        // hot loop: per k-step 4x ds_read_b128 + 128 VALU (sub + abs-add)
        #pragma unroll 6
        for (int k = 0; k < KC; ++k) {
            const float4 p0 = *(const float4*)&Pst[k * 64 + tx * 8];
            const float4 p1 = *(const float4*)&Pst[k * 64 + tx * 8 + 4];
            const float4 q0 = *(const float4*)&Wst[k * 64 + ty * 8];
            const float4 q1 = *(const float4*)&Wst[k * 64 + ty * 8 + 4];
            const float pv[8] = {p0.x, p0.y, p0.z, p0.w, p1.x, p1.y, p1.z, p1.w};
            const float wv[8] = {q0.x, q0.y, q0.z, q0.w, q1.x, q1.y, q1.z, q1.w};
            #pragma unroll
            for (int i = 0; i < 8; ++i)
                #pragma unroll
                for (int j = 0; j < 8; ++j)
                    acc[i][j] += __builtin_fabsf(pv[i] - wv[j]);
        }
    }

    // ---- cross-wave tree reduction in LDS (regions reuse staging buffer)
    float* R0 = sm;            // 4096 floats
    float* R1 = sm + 4096;     // 4096 floats
    __syncthreads();
    if (wid >= 2) {
        float* R = (wid == 2) ? R0 : R1;
        #pragma unroll
        for (int i = 0; i < 8; ++i)
            #pragma unroll
            for (int j = 0; j < 8; ++j)
                R[(i * 8 + j) * 64 + lane] = acc[i][j];
    }
    __syncthreads();
    if (wid < 2) {
        float* R = (wid == 0) ? R0 : R1;
        #pragma unroll
        for (int i = 0; i < 8; ++i)
            #pragma unroll
            for (int j = 0; j < 8; ++j)
                acc[i][j] += R[(i * 8 + j) * 64 + lane];
    }
    __syncthreads();
    if (wid == 1) {
        #pragma unroll
        for (int i = 0; i < 8; ++i)
            #pragma unroll
            for (int j = 0; j < 8; ++j)
                R0[(i * 8 + j) * 64 + lane] = acc[i][j];
    }
    __syncthreads();
    if (wid == 0) {
        #pragma unroll
        for (int i = 0; i < 8; ++i)
            #pragma unroll
            for (int j = 0; j < 8; ++j)
                acc[i][j] += R0[(i * 8 + j) * 64 + lane];
        // atomic accumulate (negated) into pre-zeroed out
        const int mo = m0 + tx * 8;          // 8-group never straddles an image (8|784)
        const int bo = mo / L_;
        const int lo = mo - bo * L_;
        float* obase = out + (size_t)bo * (F_ * L_) + (size_t)(f0 + ty * 8) * L_ + lo;
        #pragma unroll
        for (int j = 0; j < 8; ++j)
            #pragma unroll
            for (int i = 0; i < 8; ++i)
                atomicAdd(&obase[j * L_ + i], -acc[i][j]);
    }
}

__global__ __launch_bounds__(256)
void adder2d_zero(float4* __restrict__ o) {
    o[blockIdx.x * 256 + threadIdx.x] = make_float4(0.f, 0.f, 0.f, 0.f);
}

extern "C" void kernel_launch(void* const* d_in, const int* in_sizes, int n_in,
                              void* d_out, int out_size, void* d_ws, size_t ws_size,
                              hipStream_t stream) {
    const float* x = (const float*)d_in[0];   // [16,128,28,28]
    const float* W = (const float*)d_in[1];   // [128,128,3,3]
    float* out = (float*)d_out;               // [16,128,28,28]

    adder2d_zero<<<(B_ * F_ * L_ / 4) / 256, 256, 0, stream>>>((float4*)out);
    dim3 grid(M_ / TM, F_ / TF, Z);           // (196, 2, 4) = 1568 blocks
    adder2d_main<<<grid, 256, 0, stream>>>(x, W, out);
}

// Round 4
// 242.414 us; speedup vs baseline: 1.2484x; 1.2484x over previous
//
#include <hip/hip_runtime.h>

// adder2d: out[b,f,l] = -sum_k |W[f,k] - P[b,k,l]|, P = 3x3/s1/p1 im2col of x.
// M=16*784=12544, N=F=128, K=1152. fp32 exact.
// R4: single kernel. Block = 4 waves on ONE 64x64 tile, in-block K-split
// (32 ch/wave). Each wave stages its OWN LDS rows and reads only those ->
// chunk loop is barrier-free. 8x8 micro/lane => hot loop VALU-bound
// (LDS 48 cyc < VALU 64 cyc per k-step per wave-share). End: LDS tree-reduce,
// wave 0 plain coalesced stores. No atomics / ws / extra kernels.

#define B_   16
#define C_   128
#define HH   28
#define WW   28
#define F_   128
#define L_   (HH * WW)         // 784
#define K_   (C_ * 9)          // 1152
#define M_   (B_ * L_)         // 12544 = 196 * 64
#define NW   4                 // waves per block (k-split)
#define BCW  4                 // channels per chunk per wave
#define KCW  (BCW * 9)         // 36 k-rows per wave per chunk
#define KC   (KCW * NW)        // 144 rows staged per chunk (block-wide)
#define NCHUNK (32 / BCW)      // 8 chunks (each wave owns 32 channels)

__global__ __launch_bounds__(256, 2)
void adder2d_main(const float* __restrict__ x, const float* __restrict__ Wg,
                  float* __restrict__ out) {
    __shared__ float sm[2 * KC * 64];          // P rows then W rows: 73,728 B

    const int t    = threadIdx.x;
    const int wid  = t >> 6;
    const int lane = t & 63;
    const int tx   = lane & 7;                 // m-group (8 m's)
    const int ty   = lane >> 3;                // f-group (8 f's)
    const int m0   = blockIdx.x * 64;
    const int f0   = blockIdx.y * 64;

    float* Pw = sm + wid * (KCW * 64);              // this wave's P rows
    float* Ww = sm + KC * 64 + wid * (KCW * 64);    // this wave's W rows

    // ---- P staging geometry: lane stages column m = m0 + lane, 9 spatial taps
    const int mG = m0 + lane;
    const int bI = mG / L_;
    const int lP = mG - bI * L_;
    const int ho = lP / WW;
    const int wo = lP - ho * WW;
    int  roff[9];
    bool rok[9];
    #pragma unroll
    for (int r = 0; r < 9; ++r) {
        const int kh = r / 3, kw = r - 3 * (r / 3);
        const int y = ho + kh - 1, xx = wo + kw - 1;
        rok[r]  = (y >= 0) && (y < HH) && (xx >= 0) && (xx < WW);
        roff[r] = y * WW + xx;
    }
    const float* xb = x + (size_t)bI * (C_ * L_);
    // ---- W staging: lane is the f-column; this wave's 288-k segment
    const float* wrow = Wg + (size_t)(f0 + lane) * K_ + wid * (32 * 9);

    float acc[8][8];
    #pragma unroll
    for (int i = 0; i < 8; ++i)
        #pragma unroll
        for (int j = 0; j < 8; ++j) acc[i][j] = 0.0f;

    for (int ch = 0; ch < NCHUNK; ++ch) {
        // stage P: rows i = c_local*9 + r, col = lane (coalesced, 2-way-free writes)
        const float* xc = xb + (wid * 32 + ch * BCW) * L_;
        #pragma unroll
        for (int i = 0; i < KCW; ++i) {
            const int cl = i / 9, r = i - 9 * (i / 9);
            float v = 0.0f;
            if (rok[r]) v = xc[cl * L_ + roff[r]];
            Pw[i * 64 + lane] = v;
        }
        // stage W: 9 float4 loads from this lane's filter row (L2-resident)
        const float* wc = wrow + ch * KCW;
        #pragma unroll
        for (int i = 0; i < 9; ++i) {
            const float4 q = *(const float4*)&wc[i * 4];
            Ww[(i * 4 + 0) * 64 + lane] = q.x;
            Ww[(i * 4 + 1) * 64 + lane] = q.y;
            Ww[(i * 4 + 2) * 64 + lane] = q.z;
            Ww[(i * 4 + 3) * 64 + lane] = q.w;
        }
        // hot loop (barrier-free): 36 k-steps x (4 ds_read_b128 + 128 VALU)
        #pragma unroll 6
        for (int k = 0; k < KCW; ++k) {
            const float4 p0 = *(const float4*)&Pw[k * 64 + tx * 8];
            const float4 p1 = *(const float4*)&Pw[k * 64 + tx * 8 + 4];
            const float4 q0 = *(const float4*)&Ww[k * 64 + ty * 8];
            const float4 q1 = *(const float4*)&Ww[k * 64 + ty * 8 + 4];
            const float pv[8] = {p0.x, p0.y, p0.z, p0.w, p1.x, p1.y, p1.z, p1.w};
            const float wv[8] = {q0.x, q0.y, q0.z, q0.w, q1.x, q1.y, q1.z, q1.w};
            #pragma unroll
            for (int i = 0; i < 8; ++i)
                #pragma unroll
                for (int j = 0; j < 8; ++j)
                    acc[i][j] += __builtin_fabsf(pv[i] - wv[j]);
        }
    }

    // ---- cross-wave tree reduction (reuses sm; full barrier first)
    float* R0 = sm;            // 4096 floats
    float* R1 = sm + 4096;     // 4096 floats
    __syncthreads();
    if (wid >= 2) {
        float* R = (wid == 2) ? R0 : R1;
        #pragma unroll
        for (int i = 0; i < 8; ++i)
            #pragma unroll
            for (int j = 0; j < 8; ++j)
                R[(i * 8 + j) * 64 + lane] = acc[i][j];
    }
    __syncthreads();
    if (wid < 2) {
        float* R = (wid == 0) ? R0 : R1;
        #pragma unroll
        for (int i = 0; i < 8; ++i)
            #pragma unroll
            for (int j = 0; j < 8; ++j)
                acc[i][j] += R[(i * 8 + j) * 64 + lane];
    }
    __syncthreads();
    if (wid == 1) {
        #pragma unroll
        for (int i = 0; i < 8; ++i)
            #pragma unroll
            for (int j = 0; j < 8; ++j)
                R0[(i * 8 + j) * 64 + lane] = acc[i][j];
    }
    __syncthreads();
    if (wid == 0) {
        #pragma unroll
        for (int i = 0; i < 8; ++i)
            #pragma unroll
            for (int j = 0; j < 8; ++j)
                acc[i][j] += R0[(i * 8 + j) * 64 + lane];
        // plain coalesced stores (8 | 784 so an 8-m group never straddles images)
        const int mo = m0 + tx * 8;
        const int bo = mo / L_;
        const int lo = mo - bo * L_;
        float* ob = out + (size_t)bo * (F_ * L_) + (size_t)f0 * L_ + lo;
        #pragma unroll
        for (int j = 0; j < 8; ++j) {
            float* orow = ob + (size_t)(ty * 8 + j) * L_;
            *(float4*)&orow[0] = make_float4(-acc[0][j], -acc[1][j], -acc[2][j], -acc[3][j]);
            *(float4*)&orow[4] = make_float4(-acc[4][j], -acc[5][j], -acc[6][j], -acc[7][j]);
        }
    }
}

extern "C" void kernel_launch(void* const* d_in, const int* in_sizes, int n_in,
                              void* d_out, int out_size, void* d_ws, size_t ws_size,
                              hipStream_t stream) {
    const float* x = (const float*)d_in[0];   // [16,128,28,28]
    const float* W = (const float*)d_in[1];   // [128,128,3,3]
    float* out = (float*)d_out;               // [16,128,28,28]

    dim3 grid(M_ / 64, F_ / 64);              // (196, 2) = 392 blocks
    adder2d_main<<<grid, 256, 0, stream>>>(x, W, out);
}

// Round 5
// 220.095 us; speedup vs baseline: 1.3750x; 1.1014x over previous
//
#include <hip/hip_runtime.h>

// adder2d: out[b,f,l] = -sum_k |W[f,k] - P[b,k,l]|, P = 3x3/s1/p1 im2col of x.
// M=16*784=12544, N=F=128, K=1152. fp32 exact.
// R5: block = 512 threads (8 waves) on ONE 64x64 output tile, in-block K-split
// x8 (16 channels/wave). Each wave stages 2-channel chunks into PRIVATE LDS
// regions -> hot loop is barrier-free; 8x8 micro per lane keeps LDS at 75% of
// VALU demand. __launch_bounds__(512,4) caps VGPR at 128 -> 2 blocks/CU
// resident = 4 waves/SIMD for latency hiding. Tail: 3-round LDS tree reduce,
// wave 0 stores. No atomics / workspace / extra kernels.

#define B_   16
#define C_   128
#define HH   28
#define WW   28
#define F_   128
#define L_   (HH * WW)         // 784
#define K_   (C_ * 9)          // 1152
#define M_   (B_ * L_)         // 12544 = 196 * 64
#define NW   8                 // waves per block (k-split)
#define CPW  (C_ / NW)         // 16 channels per wave
#define BCW  2                 // channels per chunk per wave
#define KCW  (BCW * 9)         // 18 k-rows per wave per chunk
#define NCHUNK (CPW / BCW)     // 8 chunks per wave
#define REG  (KCW * 64)        // 1152 floats per LDS staging region (4608 B)

__global__ __launch_bounds__(512, 4)
void adder2d_main(const float* __restrict__ x, const float* __restrict__ Wg,
                  float* __restrict__ out) {
    __shared__ float sm[2 * NW * REG];         // 18432 floats = 73,728 B

    const int t    = threadIdx.x;
    const int wid  = t >> 6;                   // 0..7
    const int lane = t & 63;
    const int tx   = lane & 7;                 // m-group (8 m's)
    const int ty   = lane >> 3;                // f-group (8 f's)
    const int m0   = blockIdx.x * 64;
    const int f0   = blockIdx.y * 64;

    float* Pw = sm + wid * REG;                // this wave's P rows
    float* Ww = sm + NW * REG + wid * REG;     // this wave's W rows

    // ---- P staging geometry: lane stages column m = m0 + lane, 9 spatial taps
    const int mG = m0 + lane;
    const int bI = mG / L_;
    const int lP = mG - bI * L_;
    const int ho = lP / WW;
    const int wo = lP - ho * WW;
    int  roff[9];
    bool rok[9];
    #pragma unroll
    for (int r = 0; r < 9; ++r) {
        const int kh = r / 3, kw = r - 3 * (r / 3);
        const int y = ho + kh - 1, xx = wo + kw - 1;
        rok[r]  = (y >= 0) && (y < HH) && (xx >= 0) && (xx < WW);
        roff[r] = y * WW + xx;
    }
    const float* xb = x + (size_t)bI * (C_ * L_) + (size_t)(wid * CPW) * L_;
    // ---- W staging: lane is the f-column; this wave's 144-k segment
    const float* wrow = Wg + (size_t)(f0 + lane) * K_ + wid * (CPW * 9);

    float acc[8][8];
    #pragma unroll
    for (int i = 0; i < 8; ++i)
        #pragma unroll
        for (int j = 0; j < 8; ++j) acc[i][j] = 0.0f;

    for (int ch = 0; ch < NCHUNK; ++ch) {
        // stage P: rows i = c_local*9 + r, col = lane (coalesced, conflict-free)
        const float* xc = xb + ch * BCW * L_;
        #pragma unroll
        for (int i = 0; i < KCW; ++i) {
            const int cl = i / 9, r = i - 9 * (i / 9);
            float v = 0.0f;
            if (rok[r]) v = xc[cl * L_ + roff[r]];
            Pw[i * 64 + lane] = v;
        }
        // stage W: this lane's filter row, 18 consecutive k (L2-resident)
        const float* wc = wrow + ch * KCW;
        #pragma unroll
        for (int i = 0; i < KCW; ++i) Ww[i * 64 + lane] = wc[i];
        // hot loop (barrier-free; within-wave LDS ordering via lgkmcnt):
        // 18 k-steps x (4 ds_read_b128 + 128 VALU)
        #pragma unroll 6
        for (int k = 0; k < KCW; ++k) {
            const float4 p0 = *(const float4*)&Pw[k * 64 + tx * 8];
            const float4 p1 = *(const float4*)&Pw[k * 64 + tx * 8 + 4];
            const float4 q0 = *(const float4*)&Ww[k * 64 + ty * 8];
            const float4 q1 = *(const float4*)&Ww[k * 64 + ty * 8 + 4];
            const float pv[8] = {p0.x, p0.y, p0.z, p0.w, p1.x, p1.y, p1.z, p1.w};
            const float wv[8] = {q0.x, q0.y, q0.z, q0.w, q1.x, q1.y, q1.z, q1.w};
            #pragma unroll
            for (int i = 0; i < 8; ++i)
                #pragma unroll
                for (int j = 0; j < 8; ++j)
                    acc[i][j] += __builtin_fabsf(pv[i] - wv[j]);
        }
    }

    // ---- cross-wave tree reduction: 8 -> 4 -> 2 -> 1 (regions of 4096 floats)
    __syncthreads();
    if (wid >= 4) {
        float* R = sm + (wid - 4) * 4096;
        #pragma unroll
        for (int i = 0; i < 8; ++i)
            #pragma unroll
            for (int j = 0; j < 8; ++j)
                R[(i * 8 + j) * 64 + lane] = acc[i][j];
    }
    __syncthreads();
    if (wid < 4) {
        float* R = sm + wid * 4096;
        #pragma unroll
        for (int i = 0; i < 8; ++i)
            #pragma unroll
            for (int j = 0; j < 8; ++j)
                acc[i][j] += R[(i * 8 + j) * 64 + lane];
    }
    __syncthreads();
    if (wid == 2 || wid == 3) {
        float* R = sm + (wid - 2) * 4096;
        #pragma unroll
        for (int i = 0; i < 8; ++i)
            #pragma unroll
            for (int j = 0; j < 8; ++j)
                R[(i * 8 + j) * 64 + lane] = acc[i][j];
    }
    __syncthreads();
    if (wid < 2) {
        float* R = sm + wid * 4096;
        #pragma unroll
        for (int i = 0; i < 8; ++i)
            #pragma unroll
            for (int j = 0; j < 8; ++j)
                acc[i][j] += R[(i * 8 + j) * 64 + lane];
    }
    __syncthreads();
    if (wid == 1) {
        #pragma unroll
        for (int i = 0; i < 8; ++i)
            #pragma unroll
            for (int j = 0; j < 8; ++j)
                sm[(i * 8 + j) * 64 + lane] = acc[i][j];
    }
    __syncthreads();
    if (wid == 0) {
        #pragma unroll
        for (int i = 0; i < 8; ++i)
            #pragma unroll
            for (int j = 0; j < 8; ++j)
                acc[i][j] += sm[(i * 8 + j) * 64 + lane];
        // plain coalesced stores (8 | 784 so an 8-m group never straddles images)
        const int mo = m0 + tx * 8;
        const int bo = mo / L_;
        const int lo = mo - bo * L_;
        float* ob = out + (size_t)bo * (F_ * L_) + (size_t)f0 * L_ + lo;
        #pragma unroll
        for (int j = 0; j < 8; ++j) {
            float* orow = ob + (size_t)(ty * 8 + j) * L_;
            *(float4*)&orow[0] = make_float4(-acc[0][j], -acc[1][j], -acc[2][j], -acc[3][j]);
            *(float4*)&orow[4] = make_float4(-acc[4][j], -acc[5][j], -acc[6][j], -acc[7][j]);
        }
    }
}

extern "C" void kernel_launch(void* const* d_in, const int* in_sizes, int n_in,
                              void* d_out, int out_size, void* d_ws, size_t ws_size,
                              hipStream_t stream) {
    const float* x = (const float*)d_in[0];   // [16,128,28,28]
    const float* W = (const float*)d_in[1];   // [128,128,3,3]
    float* out = (float*)d_out;               // [16,128,28,28]

    dim3 grid(M_ / 64, F_ / 64);              // (196, 2) = 392 blocks of 512
    adder2d_main<<<grid, 512, 0, stream>>>(x, W, out);
}